// Round 1
// baseline (214.522 us; speedup 1.0000x reference)
//
#include <hip/hip_runtime.h>
#include <hip/hip_bf16.h>

typedef __bf16 bf16x8 __attribute__((ext_vector_type(8)));
typedef float f32x4 __attribute__((ext_vector_type(4)));
typedef long longx2 __attribute__((ext_vector_type(2)));
typedef int i32x8 __attribute__((ext_vector_type(8)));

#define N 8192
#define D 512
#define NS 64

// workspace layout (bytes) — ~21 MB (unchanged)
#define XS_OFF 0                            // fp8 X [N][512 B] NATURAL k-order : 4 MB
#define WT_OFF (4 * 1024 * 1024)            // bf16 WT chunked [256][64s][32i] : 1 MB
#define SQ_OFF (WT_OFF + 1024 * 1024)       // f32 sq [N] : 32 KB
#define EP_OFF (SQ_OFF + 32 * 1024)         // f32 Ep [8 chunk][64 s][8192 n] : 16 MB
#define SC_OFF (EP_OFF + 8 * 64 * 8192 * 4) // f32 S1,S2 + int cnt

// raw barrier: drain LDS ops only; leave global loads (vmcnt) in flight.
// __syncthreads() would emit s_waitcnt vmcnt(0) and kill the prefetch.
#define BAR() do { asm volatile("s_waitcnt lgkmcnt(0)" ::: "memory"); \
                   __builtin_amdgcn_s_barrier(); } while (0)

// ---------------------------------------------------------------------------
// fused prep (blocks [0,2048): X -> fp8 natural order + sq; [2048,2176): W->WT)
// MX fragments (16x16x128) want k-contiguous 32 B per lane, so Xs is stored
// in plain row-major fp8 (the old 16x16x32 interleave permutation is gone).
__global__ __launch_bounds__(256) void prep(const float* __restrict__ X,
                                            const float* __restrict__ W,
                                            unsigned char* __restrict__ Xs,
                                            float* __restrict__ sq,
                                            __bf16* __restrict__ WTs,
                                            float* __restrict__ Sacc) {
    __shared__ float T[64][65];
    int t = threadIdx.x;
    if (blockIdx.x == 0 && t == 0) {        // zero loss accumulators + counter
        Sacc[0] = 0.f; Sacc[1] = 0.f; ((int*)Sacc)[2] = 0;
    }
    if (blockIdx.x < 2048) {
        int row = blockIdx.x * 4 + (t >> 6);
        int l = t & 63;
        const float* src = X + (size_t)row * D + l * 8;
        float4 v0 = *(const float4*)src;
        float4 v1 = *(const float4*)(src + 4);
        int w0 = __builtin_amdgcn_cvt_pk_fp8_f32(v0.x, v0.y, 0, false);
        w0     = __builtin_amdgcn_cvt_pk_fp8_f32(v0.z, v0.w, w0, true);
        int w1 = __builtin_amdgcn_cvt_pk_fp8_f32(v1.x, v1.y, 0, false);
        w1     = __builtin_amdgcn_cvt_pk_fp8_f32(v1.z, v1.w, w1, true);
        uint2 pk = make_uint2((unsigned)w0, (unsigned)w1);
        *(uint2*)(Xs + (size_t)row * 512 + l * 8) = pk;   // natural k order
        float acc = v0.x*v0.x + v0.y*v0.y + v0.z*v0.z + v0.w*v0.w
                  + v1.x*v1.x + v1.y*v1.y + v1.z*v1.z + v1.w*v1.w;
        for (int off = 32; off > 0; off >>= 1) acc += __shfl_down(acc, off);
        if (l == 0) sq[row] = acc;
    } else {
        int i0 = (blockIdx.x - 2048) * 64;
        for (int j = 0; j < 16; ++j) {
            int idx = t + 256 * j;
            T[idx & 63][idx >> 6] = W[(size_t)(i0 + (idx >> 6)) * NS + (idx & 63)];
        }
        __syncthreads();
        for (int h = 0; h < 2; ++h)
            for (int j = 0; j < 8; ++j) {
                int idx = t + 256 * j;                  // 0..2047
                int s = idx >> 5, il = idx & 31;
                WTs[(size_t)((i0 >> 5) + h) * 2048 + idx] = (__bf16)T[s][h * 32 + il];
            }
    }
}

// ---------------------------------------------------------------------------
// main, round-10 (MX): grid (64 n-blocks, 8 i-chunks). Per block, 8 its of 128 i.
//  - Gram 128x128 via mfma_scale_f32_16x16x128_f8f6f4 (scale=1.0 -> bit-identical
//    fp8 math at 2.27x the non-scaled rate). K=512 -> 4 MFMA steps of 16.
//  - B-panel: kc128=0 cached in VGPRs (32 regs), kc128 1..3 in LDS XnHi
//    [128][384+16pad]. A streams through a single 16 KB Xi buffer that is
//    UNIONED with KT (never live simultaneously) -> LDS total 69632, 2 blk/CU.
//  - Xi 16B-blocks XOR-swizzled by row&7: the quad*32 fragment reads would
//    otherwise only touch banks 8q..8q+3 per b128 (2x conflict).
//  - All barriers are raw s_barrier + lgkmcnt(0): global prefetch stays in
//    flight across barriers (syncthreads' vmcnt(0) drain defeated prefetch).
//  - exp epilogue + bf16 E-phase (WT frags direct from global) unchanged.
// Walls (r4-r9 + this round): LDS <= 80K for 2 blocks/CU; E-phase must be
// bf16; reg budget 256/wave at 2 waves/SIMD -> only 1 kc128 B-cache fits.
__global__ __launch_bounds__(256, 2) void kpca_main(
        const unsigned char* __restrict__ Xs, const __bf16* __restrict__ WTs,
        const float* __restrict__ sq, float* __restrict__ Ep) {
    __shared__ __align__(16) unsigned char XiKT[18432];   // Xi[128][128] ∪ KT[128][72]bf16
    __shared__ __align__(16) unsigned char XnHi[128 * 400]; // 384 B data + 16 pad
    unsigned char* Xi = XiKT;
    __bf16* KT = (__bf16*)XiKT;

    const int t = threadIdx.x;
    const int w = t >> 6, l = t & 63;
    const int quad = l >> 4, l15 = l & 15;
    const int wm = w >> 1, wn = w & 1;
    const int n0 = blockIdx.x * 128;
    const int ic0 = blockIdx.y * 1024;

    union U8 { longx2 h[2]; i32x8 v; };

    // ---- prologue: B-frag VGPR cache (kc128=0) + XnHi panel (k 128..511)
    U8 bc[4];
    {
        const unsigned char* Bb = Xs + (size_t)(n0 + wn * 64 + l15) * 512 + quad * 32;
        #pragma unroll
        for (int nt = 0; nt < 4; ++nt) {
            bc[nt].h[0] = *(const longx2*)(Bb + nt * 8192);
            bc[nt].h[1] = *(const longx2*)(Bb + nt * 8192 + 16);
        }
    }
    {
        int r = t >> 1, h = t & 1;
        const unsigned char* g = Xs + (size_t)(n0 + r) * 512 + 128 + h * 192;
        unsigned char* d = XnHi + r * 400 + h * 192;
        #pragma unroll
        for (int j = 0; j < 12; ++j)
            *(uint4*)(d + j * 16) = *(const uint4*)(g + j * 16);
    }
    float sqn_v[4];
    #pragma unroll
    for (int nt = 0; nt < 4; ++nt)
        sqn_v[nt] = sq[n0 + wn * 64 + nt * 16 + l15];

    f32x4 accE[4][2];
    #pragma unroll
    for (int st = 0; st < 4; ++st)
        for (int n2 = 0; n2 < 2; ++n2)
            accE[st][n2] = (f32x4){0.f, 0.f, 0.f, 0.f};

    // staging geometry: per j, 8 lanes cover one row's 128 B contiguously
    const int rB = t >> 3;                 // 0..31 (row within 32-row group)
    const int cB = (t & 7) * 16;           // 16-B column
    const int swoff = (((t & 7) ^ ((t >> 3) & 7)) << 4);   // write-side swizzle

    // a-frag read offsets (swizzled 16-B block pair for k = quad*32..+32)
    const int oswL = (((2 * quad)     ^ (l15 & 7)) << 4);
    const int oswH = (((2 * quad + 1) ^ (l15 & 7)) << 4);

    // prestage chunk (it=0, ks=0): rows ic0..+127, k-bytes 0..127
    {
        const unsigned char* g = Xs + (size_t)(ic0 + rB) * 512 + cB;
        #pragma unroll
        for (int j = 0; j < 4; ++j)
            *(uint4*)(Xi + (size_t)(j * 32 + rB) * 128 + swoff) =
                *(const uint4*)(g + (size_t)j * 32 * 512);
    }

    uint4 q[4];   // prefetch regs, carried across the E phase at it boundaries

    for (int it = 0; it < 8; ++it) {
        const int i0 = ic0 + it * 128;
        f32x4 accG[4][4];
        #pragma unroll
        for (int mt = 0; mt < 4; ++mt)
            for (int nt = 0; nt < 4; ++nt)
                accG[mt][nt] = (f32x4){0.f, 0.f, 0.f, 0.f};

        if (it > 0) {
            BAR();   // E-phase KT reads done -> Xi region free
            #pragma unroll
            for (int j = 0; j < 4; ++j)
                *(uint4*)(Xi + (size_t)(j * 32 + rB) * 128 + swoff) = q[j];
        }

        #pragma unroll
        for (int ks = 0; ks < 4; ++ks) {
            // prefetch next chunk (this it's ks+1, or next it's ks=0)
            const bool stage = (ks < 3) || (it < 7);
            if (stage) {
                const int itn = (ks < 3) ? it : it + 1;
                const int ksn = (ks < 3) ? ks + 1 : 0;
                const unsigned char* g =
                    Xs + (size_t)(ic0 + itn * 128 + rB) * 512 + ksn * 128 + cB;
                #pragma unroll
                for (int j = 0; j < 4; ++j)
                    q[j] = *(const uint4*)(g + (size_t)j * 32 * 512);
            }
            BAR();   // chunk ks stores visible (prologue / it-top / prev ks)

            U8 a[4], bb[4];
            const unsigned char* abase = Xi + (wm * 64 + l15) * 128;
            #pragma unroll
            for (int mt = 0; mt < 4; ++mt) {
                a[mt].h[0] = *(const longx2*)(abase + mt * 2048 + oswL);
                a[mt].h[1] = *(const longx2*)(abase + mt * 2048 + oswH);
            }
            if (ks == 0) {
                #pragma unroll
                for (int nt = 0; nt < 4; ++nt) bb[nt] = bc[nt];
            } else {
                const unsigned char* bbase =
                    XnHi + (wn * 64 + l15) * 400 + (ks - 1) * 128 + quad * 32;
                #pragma unroll
                for (int nt = 0; nt < 4; ++nt) {
                    bb[nt].h[0] = *(const longx2*)(bbase + nt * 6400);
                    bb[nt].h[1] = *(const longx2*)(bbase + nt * 6400 + 16);
                }
            }
            __builtin_amdgcn_s_setprio(1);
            #pragma unroll
            for (int mt = 0; mt < 4; ++mt)
                #pragma unroll
                for (int nt = 0; nt < 4; ++nt)
                    accG[mt][nt] = __builtin_amdgcn_mfma_scale_f32_16x16x128_f8f6f4(
                        a[mt].v, bb[nt].v, accG[mt][nt],
                        0, 0,                 // cbsz=FP8(e4m3), blgp=FP8(e4m3)
                        0, 0x7F7F7F7F,        // scale_a opsel, scale_a = 1.0 (E8M0 127)
                        0, 0x7F7F7F7F);       // scale_b opsel, scale_b = 1.0
            __builtin_amdgcn_s_setprio(0);

            if (ks < 3) {
                BAR();   // all Xi reads of chunk ks done
                #pragma unroll
                for (int j = 0; j < 4; ++j)
                    *(uint4*)(Xi + (size_t)(j * 32 + rB) * 128 + swoff) = q[j];
            }
            // ks==3: q (next it's chunk 0) held in regs across the E phase
        }

        // ---- epilogue: d2 -> exp -> packed bf16 (accG dies here)
        uint2 pk[4][4];
        #pragma unroll
        for (int mt = 0; mt < 4; ++mt) {
            f32x4 si = *(const f32x4*)(sq + i0 + wm * 64 + mt * 16 + quad * 4);
            #pragma unroll
            for (int nt = 0; nt < 4; ++nt) {
                float sn = sqn_v[nt];
                union { __bf16 h[4]; uint2 u; } u;
                #pragma unroll
                for (int r = 0; r < 4; ++r) {
                    float d2 = si[r] + sn - 2.0f * accG[mt][nt][r];
                    u.h[r] = (__bf16)__expf(d2 * -9.765625e-4f);   // exp(-d2/1024)
                }
                pk[mt][nt] = u.u;
            }
        }

        const __bf16* wslab = WTs + (size_t)(i0 >> 5) * 2048;
        bf16x8 aw[2][4];
        #pragma unroll
        for (int kc2 = 0; kc2 < 2; ++kc2)
            for (int st = 0; st < 4; ++st)
                aw[kc2][st] = *(const bf16x8*)(wslab + kc2 * 2048 +
                                               (st * 16 + l15) * 32 + quad * 8);

        BAR();             // A: Gram Xi reads + prev KT reads done
        if (wm == 0) {     // half 0: i-local 0..63
            #pragma unroll
            for (int mt = 0; mt < 4; ++mt)
                for (int nt = 0; nt < 4; ++nt)
                    *(uint2*)(KT + (wn * 64 + nt * 16 + l15) * 72 + mt * 16 + quad * 4)
                        = pk[mt][nt];
        }
        BAR();             // B: KT half-0 visible
        #pragma unroll
        for (int kc2 = 0; kc2 < 2; ++kc2) {
            bf16x8 bk[2];
            for (int n2 = 0; n2 < 2; ++n2)
                bk[n2] = *(const bf16x8*)(KT + (w * 32 + n2 * 16 + l15) * 72 +
                                          kc2 * 32 + quad * 8);
            #pragma unroll
            for (int st = 0; st < 4; ++st)
                for (int n2 = 0; n2 < 2; ++n2)
                    accE[st][n2] = __builtin_amdgcn_mfma_f32_16x16x32_bf16(
                        aw[kc2][st], bk[n2], accE[st][n2], 0, 0, 0);
        }
        #pragma unroll
        for (int kc2 = 0; kc2 < 2; ++kc2)      // second half (kc2 2,3)
            for (int st = 0; st < 4; ++st)
                aw[kc2][st] = *(const bf16x8*)(wslab + (kc2 + 2) * 2048 +
                                               (st * 16 + l15) * 32 + quad * 8);
        BAR();             // C: half-0 E reads done
        if (wm == 1) {     // half 1: i-local 64..127
            #pragma unroll
            for (int mt = 0; mt < 4; ++mt)
                for (int nt = 0; nt < 4; ++nt)
                    *(uint2*)(KT + (wn * 64 + nt * 16 + l15) * 72 + mt * 16 + quad * 4)
                        = pk[mt][nt];
        }
        BAR();             // D: KT half-1 visible
        #pragma unroll
        for (int kc2 = 0; kc2 < 2; ++kc2) {
            bf16x8 bk[2];
            for (int n2 = 0; n2 < 2; ++n2)
                bk[n2] = *(const bf16x8*)(KT + (w * 32 + n2 * 16 + l15) * 72 +
                                          kc2 * 32 + quad * 8);
            #pragma unroll
            for (int st = 0; st < 4; ++st)
                for (int n2 = 0; n2 < 2; ++n2)
                    accE[st][n2] = __builtin_amdgcn_mfma_f32_16x16x32_bf16(
                        aw[kc2][st], bk[n2], accE[st][n2], 0, 0, 0);
        }
    }

    // ---- per-chunk E partial: plain stores
    float* ep = Ep + (size_t)blockIdx.y * (NS * N);
    #pragma unroll
    for (int st = 0; st < 4; ++st)
        for (int n2 = 0; n2 < 2; ++n2)
            for (int r = 0; r < 4; ++r) {
                int s = st * 16 + quad * 4 + r;
                int n = n0 + w * 32 + n2 * 16 + l15;
                ep[(size_t)s * N + n] = accE[st][n2][r];
            }
}

// ---------------------------------------------------------------------------
// loss: 256 blocks = 64 s x 4 n-chunks; sums the 8 E partials, reduces;
// last block finalizes the scalar.
__global__ __launch_bounds__(256) void loss_kernel(const float* __restrict__ Ep,
                                                   const __bf16* __restrict__ WTs,
                                                   const float* __restrict__ lam,
                                                   float* __restrict__ Sacc,
                                                   float* __restrict__ out) {
    int s = blockIdx.x >> 2;
    int nb = (blockIdx.x & 3) * 2048;
    int t = threadIdx.x;
    float a1 = 0.f, a2 = 0.f;
    for (int j = 0; j < 8; ++j) {
        int n = nb + t + j * 256;
        float e = 0.f;
        #pragma unroll
        for (int c = 0; c < 8; ++c)
            e += Ep[(size_t)c * (NS * N) + (size_t)s * N + n];
        a1 += e * e;
        a2 += e * (float)WTs[(size_t)(n >> 5) * 2048 + s * 32 + (n & 31)];
    }
    for (int off = 32; off > 0; off >>= 1) {
        a1 += __shfl_down(a1, off);
        a2 += __shfl_down(a2, off);
    }
    __shared__ float r1[4], r2[4];
    int wv = t >> 6, ln = t & 63;
    if (ln == 0) { r1[wv] = a1; r2[wv] = a2; }
    __syncthreads();
    if (t == 0) {
        atomicAdd(Sacc + 0, lam[s] * (r1[0] + r1[1] + r1[2] + r1[3]));
        atomicAdd(Sacc + 1, r2[0] + r2[1] + r2[2] + r2[3]);
        __threadfence();
        int prev = atomicAdd((int*)Sacc + 2, 1);
        if (prev == 255) {                       // last block finalizes
            __threadfence();
            volatile float* vs = (volatile float*)Sacc;
            float L = 0.5f * (vs[1] - vs[0]);    // loss1=-S1/2, loss2=S2/2
            out[0] = L + 0.05f * L * L;          // C_STAB/2 = 0.05
        }
    }
}

// ---------------------------------------------------------------------------
extern "C" void kernel_launch(void* const* d_in, const int* in_sizes, int n_in,
                              void* d_out, int out_size, void* d_ws, size_t ws_size,
                              hipStream_t stream) {
    const float* X   = (const float*)d_in[0];   // [8192][512]
    const float* W   = (const float*)d_in[1];   // [8192][64]
    const float* lam = (const float*)d_in[2];   // [64]
    float* out = (float*)d_out;
    char* ws = (char*)d_ws;
    unsigned char* Xs = (unsigned char*)(ws + XS_OFF);
    __bf16* WTs = (__bf16*)(ws + WT_OFF);
    float* sq   = (float*)(ws + SQ_OFF);
    float* Ep   = (float*)(ws + EP_OFF);
    float* Sacc = (float*)(ws + SC_OFF);

    prep<<<2048 + 128, 256, 0, stream>>>(X, W, Xs, sq, WTs, Sacc);
    kpca_main<<<dim3(64, 8), 256, 0, stream>>>(Xs, WTs, sq, Ep);
    loss_kernel<<<256, 256, 0, stream>>>(Ep, WTs, lam, Sacc, out);
}